// Round 2
// baseline (41287.143 us; speedup 1.0000x reference)
//
#include <hip/hip_runtime.h>
#include <cstddef>

// FDRNN: fuzzy -> FC(200->1024->1024->1024->128) -> 2-layer tanh RNN (H=512)
// B=64, S=512 -> 32768 rows.
//
// R1 change: RNN recurrence rewritten as 256 co-resident blocks (64 batches x
// 4 output-slices) with W_hh register-resident (128 VGPR/thread) and
// cross-block h exchange via device-scope release/acquire counters.
// R0 was per-CU L2-BW bound (1MB W stream/step -> VALUBusy 12.5% predicted,
// 12.3% measured); this removes all steady-state W traffic.

__global__ void fuzzy_kernel(const float* __restrict__ x, const float* __restrict__ fp,
                             float* __restrict__ z, int nrows) {
  int idx = blockIdx.x * blockDim.x + threadIdx.x;
  int total = nrows * 200;
  if (idx >= total) return;
  int r = idx / 200;
  int f = idx - r * 200;       // f = k*50 + i
  int i = f % 50;
  float xv = x[r * 50 + i];
  float mu = fp[2 * f];
  float sg = fp[2 * f + 1];
  float d = xv - mu;
  z[idx] = expf(-(d * d) / sg);
}

// C[M,N] = A[M,K] @ W[N,K]^T + b1 (+ b2). Requires M%128==0, N%128==0, K%8==0.
__global__ __launch_bounds__(256) void gemm_bias(
    const float* __restrict__ A, const float* __restrict__ W,
    const float* __restrict__ b1, const float* __restrict__ b2,
    float* __restrict__ C, int M, int N, int K) {
  __shared__ float As[8][128];
  __shared__ float Bs[8][128];
  int tid = threadIdx.x;
  int bm = blockIdx.y * 128;
  int bn = blockIdx.x * 128;
  int ar = tid >> 1;
  int ac = (tid & 1) * 4;
  int ty = tid >> 4;
  int tx = tid & 15;

  float acc[8][8];
#pragma unroll
  for (int i = 0; i < 8; i++)
#pragma unroll
    for (int j = 0; j < 8; j++) acc[i][j] = 0.f;

  const float* Arow = A + (size_t)(bm + ar) * K + ac;
  const float* Wrow = W + (size_t)(bn + ar) * K + ac;

  for (int k0 = 0; k0 < K; k0 += 8) {
    float4 av = *(const float4*)(Arow + k0);
    float4 bv = *(const float4*)(Wrow + k0);
    __syncthreads();
    As[ac + 0][ar] = av.x; As[ac + 1][ar] = av.y;
    As[ac + 2][ar] = av.z; As[ac + 3][ar] = av.w;
    Bs[ac + 0][ar] = bv.x; Bs[ac + 1][ar] = bv.y;
    Bs[ac + 2][ar] = bv.z; Bs[ac + 3][ar] = bv.w;
    __syncthreads();
#pragma unroll
    for (int kk = 0; kk < 8; kk++) {
      float a0[8], bb[8];
      *(float4*)&a0[0] = *(const float4*)&As[kk][ty * 8];
      *(float4*)&a0[4] = *(const float4*)&As[kk][ty * 8 + 4];
      *(float4*)&bb[0] = *(const float4*)&Bs[kk][tx * 8];
      *(float4*)&bb[4] = *(const float4*)&Bs[kk][tx * 8 + 4];
#pragma unroll
      for (int i = 0; i < 8; i++)
#pragma unroll
        for (int j = 0; j < 8; j++)
          acc[i][j] = fmaf(a0[i], bb[j], acc[i][j]);
    }
  }

  float bj[8];
#pragma unroll
  for (int j = 0; j < 8; j++) {
    int n = bn + tx * 8 + j;
    bj[j] = b1[n] + (b2 ? b2[n] : 0.f);
  }
#pragma unroll
  for (int i = 0; i < 8; i++) {
    int row = bm + ty * 8 + i;
    float* Crow = C + (size_t)row * N + bn + tx * 8;
    float4 v0 = {acc[i][0] + bj[0], acc[i][1] + bj[1],
                 acc[i][2] + bj[2], acc[i][3] + bj[3]};
    float4 v1 = {acc[i][4] + bj[4], acc[i][5] + bj[5],
                 acc[i][6] + bj[6], acc[i][7] + bj[7]};
    *(float4*)Crow = v0;
    *(float4*)(Crow + 4) = v1;
  }
}

__global__ void transpose512(const float* __restrict__ W, float* __restrict__ WT) {
  __shared__ float tile[32][33];
  int bx = blockIdx.x * 32, by = blockIdx.y * 32;
  int tx = threadIdx.x, ty = threadIdx.y;  // block (32,8)
#pragma unroll
  for (int j = 0; j < 32; j += 8)
    tile[ty + j][tx] = W[(size_t)(by + ty + j) * 512 + bx + tx];
  __syncthreads();
#pragma unroll
  for (int j = 0; j < 32; j += 8)
    WT[(size_t)(bx + ty + j) * 512 + by + tx] = tile[tx][ty + j];
}

__global__ void init_rnn_state(float* __restrict__ hA, float* __restrict__ hB,
                               int* __restrict__ cnt) {
  int i = blockIdx.x * blockDim.x + threadIdx.x;
  if (i < 65536) { hA[i] = 0.f; hB[i] = 0.f; }
  if (i < 128) cnt[i] = 0;
}

// 256 blocks = 64 batches x 4 slices of 128 outputs. One block per CU,
// all co-resident (VGPR<=256 via launch_bounds, LDS 11KB).
// Thread (og=tid>>4, jblk=tid&15): outputs obase..obase+3, j in [jblk*32, +32).
// W fragment (32 x float4) lives in VGPRs for the whole kernel.
// h exchange: hbuf[2][64][512] parity double-buffer + per-batch monotonic
// counter, device-scope release/acquire (batch-mates are XCD-local by
// round-robin heuristic; correctness from agent-scope semantics).
__global__ __launch_bounds__(512, 2) void rnn_sync_k(
    const float* __restrict__ pre,   // [64][512][512], includes both biases
    const float* __restrict__ WT,    // [512][512], WT[j][o] = w_hh[o][j]
    float* __restrict__ out,         // [64][512][512]
    float* __restrict__ hbuf,        // [2][64][512]
    int* __restrict__ cnt) {         // [64]
  const int bid = blockIdx.x;
  const int b = bid & 63;
  const int slice = bid >> 6;
  const int tid = threadIdx.x;
  const int jblk = tid & 15;
  const int og = tid >> 4;
  const int obase = slice * 128 + og * 4;

  // Register-resident W fragment: w4[jj] = WT[jblk*32+jj][obase..obase+3]
  float4 w4[32];
  {
    const float* wp = WT + (size_t)(jblk * 32) * 512 + obase;
#pragma unroll
    for (int jj = 0; jj < 32; jj++)
      w4[jj] = *(const float4*)(wp + (size_t)jj * 512);
  }

  __shared__ float hs[16][36];      // hs[jblk][jj], padded: 2-way max (free)
  __shared__ float part[128][17];   // partials, padded: 2-way max

  const float* preb = pre + (size_t)b * 512 * 512 + slice * 128;
  float* outb = out + (size_t)b * 512 * 512 + slice * 128;
  float* hb0 = hbuf + (size_t)b * 512;           // parity 0
  float* hb1 = hbuf + (size_t)(64 + b) * 512;    // parity 1
  int* c = cnt + b;

  for (int t = 0; t < 512; t++) {
    // Wait until all 4 slices finished step t-1 (cnt reaches 4t).
    if (tid == 0) {
      int target = 4 * t;
      while (__hip_atomic_load(c, __ATOMIC_ACQUIRE, __HIP_MEMORY_SCOPE_AGENT) < target) {
      }
    }
    __syncthreads();
    // Stage h_{t-1} (parity (t-1)&1) into LDS; agent-scope load bypasses
    // stale L1 (t=0 reads zeroed parity-1 buffer).
    {
      const float* hprev = (t & 1) ? hb0 : hb1;
      float hv = __hip_atomic_load(&hprev[tid], __ATOMIC_RELAXED,
                                   __HIP_MEMORY_SCOPE_AGENT);
      hs[tid >> 5][tid & 31] = hv;
    }
    __syncthreads();

    float4 h4[8];
#pragma unroll
    for (int r = 0; r < 8; r++)
      h4[r] = *(const float4*)&hs[jblk][r * 4];
    float a0 = 0.f, a1 = 0.f, a2 = 0.f, a3 = 0.f;
#pragma unroll
    for (int jj = 0; jj < 32; jj++) {
      float hv = ((const float*)h4)[jj];
      a0 = fmaf(w4[jj].x, hv, a0);
      a1 = fmaf(w4[jj].y, hv, a1);
      a2 = fmaf(w4[jj].z, hv, a2);
      a3 = fmaf(w4[jj].w, hv, a3);
    }
    part[og * 4 + 0][jblk] = a0;
    part[og * 4 + 1][jblk] = a1;
    part[og * 4 + 2][jblk] = a2;
    part[og * 4 + 3][jblk] = a3;
    __syncthreads();

    if (tid < 128) {
      float s = 0.f;
#pragma unroll
      for (int k = 0; k < 16; k++) s += part[tid][k];
      float hn = tanhf(preb[(size_t)t * 512 + tid] + s);
      float* hcur = (t & 1) ? hb1 : hb0;
      hcur[slice * 128 + tid] = hn;
      outb[(size_t)t * 512 + tid] = hn;
    }
    __threadfence();     // writers: drain + make agent-visible
    __syncthreads();     // all writers fenced before the release-add
    if (tid == 0)
      __hip_atomic_fetch_add(c, 1, __ATOMIC_RELEASE, __HIP_MEMORY_SCOPE_AGENT);
  }
}

extern "C" void kernel_launch(void* const* d_in, const int* in_sizes, int n_in,
                              void* d_out, int out_size, void* d_ws, size_t ws_size,
                              hipStream_t stream) {
  const float* x     = (const float*)d_in[0];
  const float* fp    = (const float*)d_in[1];
  const float* fc0_w = (const float*)d_in[2];
  const float* fc0_b = (const float*)d_in[3];
  const float* fc1_w = (const float*)d_in[4];
  const float* fc1_b = (const float*)d_in[5];
  const float* fc2_w = (const float*)d_in[6];
  const float* fc2_b = (const float*)d_in[7];
  const float* fc3_w = (const float*)d_in[8];
  const float* fc3_b = (const float*)d_in[9];
  const float* w_ih0 = (const float*)d_in[10];
  const float* w_hh0 = (const float*)d_in[11];
  const float* b_ih0 = (const float*)d_in[12];
  const float* b_hh0 = (const float*)d_in[13];
  const float* w_ih1 = (const float*)d_in[14];
  const float* w_hh1 = (const float*)d_in[15];
  const float* b_ih1 = (const float*)d_in[16];
  const float* b_hh1 = (const float*)d_in[17];
  float* out = (float*)d_out;
  float* ws  = (float*)d_ws;

  float* pre = ws;                    // 16,777,216
  float* t0  = pre + 16777216;        // 4,194,304
  float* t1  = t0 + 4194304;          // 4,194,304
  float* zc  = t1 + 4194304;          // 819,200 (free during RNN phase)
  float* f3  = zc + 819200;           // 524,288
  float* WT0 = f3 + 524288;           // 262,144
  float* WT1 = WT0 + 262144;          // 262,144
  // RNN exchange state overlaps zc (only used after the FC loop finishes):
  float* hbufA = zc;                  // 65,536
  float* hbufB = zc + 65536;          // 65,536
  int*   cnt   = (int*)(zc + 131072); // 128 ints (layer0: [0:64), layer1: [64:128))

  transpose512<<<dim3(16, 16), dim3(32, 8), 0, stream>>>(w_hh0, WT0);
  transpose512<<<dim3(16, 16), dim3(32, 8), 0, stream>>>(w_hh1, WT1);

  const int CH = 4096;  // 32768 rows in 8 chunks
  for (int c = 0; c < 8; c++) {
    size_t row0 = (size_t)c * CH;
    fuzzy_kernel<<<(CH * 200 + 255) / 256, 256, 0, stream>>>(x + row0 * 50, fp, zc, CH);
    gemm_bias<<<dim3(8, 32), 256, 0, stream>>>(zc, fc0_w, fc0_b, nullptr, t0, CH, 1024, 200);
    gemm_bias<<<dim3(8, 32), 256, 0, stream>>>(t0, fc1_w, fc1_b, nullptr, t1, CH, 1024, 1024);
    gemm_bias<<<dim3(8, 32), 256, 0, stream>>>(t1, fc2_w, fc2_b, nullptr, t0, CH, 1024, 1024);
    gemm_bias<<<dim3(1, 32), 256, 0, stream>>>(t0, fc3_w, fc3_b, nullptr, f3, CH, 128, 1024);
    gemm_bias<<<dim3(4, 32), 256, 0, stream>>>(f3, w_ih0, b_ih0, b_hh0,
                                               pre + row0 * 512, CH, 512, 128);
  }

  // Zero h double-buffers + counters (ws is poisoned each call).
  init_rnn_state<<<(65536 + 255) / 256, 256, 0, stream>>>(hbufA, hbufB, cnt);

  // RNN layer 0: pre -> h0 sequence (staged in d_out)
  rnn_sync_k<<<256, 512, 0, stream>>>(pre, WT0, out, hbufA, cnt);
  // pre1 = h0 @ w_ih1^T + b_ih1 + b_hh1
  gemm_bias<<<dim3(4, 256), 256, 0, stream>>>(out, w_ih1, b_ih1, b_hh1, pre, 32768, 512, 512);
  // RNN layer 1: pre -> final output
  rnn_sync_k<<<256, 512, 0, stream>>>(pre, WT1, out, hbufB, cnt + 64);
}

// Round 3
// 8008.460 us; speedup vs baseline: 5.1554x; 5.1554x over previous
//
#include <hip/hip_runtime.h>
#include <hip/hip_fp16.h>
#include <cstddef>

// FDRNN: fuzzy -> FC(200->1024->1024->1024->128) -> 2-layer tanh RNN (H=512)
// B=64, S=512 -> 32768 rows.
//
// R2 post-mortem: per-step cross-workgroup sync = 40-90us/step (threadfence
// L2 writebacks + acquire-spin), and the "register-resident" W spilled
// (VGPR=84, +34GB scratch traffic). Reverted to single-block-per-batch.
// R3 change: RNN W_hh streamed as packed fp16 (16B/lane loads, v_dot2_f32_f16,
// fp32 accum). Halves the per-step W bytes -> per-CU load-port model says
// ~2.1ms/layer (was 4.1). fp16 W rel err 2^-12 -> absmax stays < 0.004.

__global__ void fuzzy_kernel(const float* __restrict__ x, const float* __restrict__ fp,
                             float* __restrict__ z, int nrows) {
  int idx = blockIdx.x * blockDim.x + threadIdx.x;
  int total = nrows * 200;
  if (idx >= total) return;
  int r = idx / 200;
  int f = idx - r * 200;       // f = k*50 + i
  int i = f % 50;
  float xv = x[r * 50 + i];
  float mu = fp[2 * f];
  float sg = fp[2 * f + 1];
  float d = xv - mu;
  z[idx] = expf(-(d * d) / sg);
}

// C[M,N] = A[M,K] @ W[N,K]^T + b1 (+ b2). Requires M%128==0, N%128==0, K%8==0.
__global__ __launch_bounds__(256) void gemm_bias(
    const float* __restrict__ A, const float* __restrict__ W,
    const float* __restrict__ b1, const float* __restrict__ b2,
    float* __restrict__ C, int M, int N, int K) {
  __shared__ float As[8][128];
  __shared__ float Bs[8][128];
  int tid = threadIdx.x;
  int bm = blockIdx.y * 128;
  int bn = blockIdx.x * 128;
  int ar = tid >> 1;
  int ac = (tid & 1) * 4;
  int ty = tid >> 4;
  int tx = tid & 15;

  float acc[8][8];
#pragma unroll
  for (int i = 0; i < 8; i++)
#pragma unroll
    for (int j = 0; j < 8; j++) acc[i][j] = 0.f;

  const float* Arow = A + (size_t)(bm + ar) * K + ac;
  const float* Wrow = W + (size_t)(bn + ar) * K + ac;

  for (int k0 = 0; k0 < K; k0 += 8) {
    float4 av = *(const float4*)(Arow + k0);
    float4 bv = *(const float4*)(Wrow + k0);
    __syncthreads();
    As[ac + 0][ar] = av.x; As[ac + 1][ar] = av.y;
    As[ac + 2][ar] = av.z; As[ac + 3][ar] = av.w;
    Bs[ac + 0][ar] = bv.x; Bs[ac + 1][ar] = bv.y;
    Bs[ac + 2][ar] = bv.z; Bs[ac + 3][ar] = bv.w;
    __syncthreads();
#pragma unroll
    for (int kk = 0; kk < 8; kk++) {
      float a0[8], bb[8];
      *(float4*)&a0[0] = *(const float4*)&As[kk][ty * 8];
      *(float4*)&a0[4] = *(const float4*)&As[kk][ty * 8 + 4];
      *(float4*)&bb[0] = *(const float4*)&Bs[kk][tx * 8];
      *(float4*)&bb[4] = *(const float4*)&Bs[kk][tx * 8 + 4];
#pragma unroll
      for (int i = 0; i < 8; i++)
#pragma unroll
        for (int j = 0; j < 8; j++)
          acc[i][j] = fmaf(a0[i], bb[j], acc[i][j]);
    }
  }

  float bj[8];
#pragma unroll
  for (int j = 0; j < 8; j++) {
    int n = bn + tx * 8 + j;
    bj[j] = b1[n] + (b2 ? b2[n] : 0.f);
  }
#pragma unroll
  for (int i = 0; i < 8; i++) {
    int row = bm + ty * 8 + i;
    float* Crow = C + (size_t)row * N + bn + tx * 8;
    float4 v0 = {acc[i][0] + bj[0], acc[i][1] + bj[1],
                 acc[i][2] + bj[2], acc[i][3] + bj[3]};
    float4 v1 = {acc[i][4] + bj[4], acc[i][5] + bj[5],
                 acc[i][6] + bj[6], acc[i][7] + bj[7]};
    *(float4*)Crow = v0;
    *(float4*)(Crow + 4) = v1;
  }
}

// Pack w_hh (fp32 [512][512] row-major) into QW: QW[j4*512 + o] is a 16B
// group of 8 fp16 = w_hh[o][8*j4 .. 8*j4+7]. Lane o's load of QW[j4*512+o]
// is 16B/lane, lane-consecutive -> perfectly coalesced.
__global__ void pack_whh_fp16(const float* __restrict__ W, float4* __restrict__ QW) {
  int idx = blockIdx.x * blockDim.x + threadIdx.x;  // 0..32767
  if (idx >= 32768) return;
  int j4 = idx >> 9;
  int o = idx & 511;
  const float* src = W + (size_t)o * 512 + j4 * 8;
  __align__(16) __half2 p[4];
#pragma unroll
  for (int k = 0; k < 4; k++)
    p[k] = __halves2half2(__float2half(src[2 * k]), __float2half(src[2 * k + 1]));
  QW[idx] = *(const float4*)p;
}

typedef _Float16 v2h __attribute__((ext_vector_type(2)));

__device__ __forceinline__ float dot2acc(float wbits, float hbits, float acc) {
#if __has_builtin(__builtin_amdgcn_fdot2)
  return __builtin_amdgcn_fdot2(__builtin_bit_cast(v2h, wbits),
                                __builtin_bit_cast(v2h, hbits), acc, false);
#else
  float2 wf = __half22float2(__builtin_bit_cast(__half2, wbits));
  float2 hf = __half22float2(__builtin_bit_cast(__half2, hbits));
  return fmaf(wf.x, hf.x, fmaf(wf.y, hf.y, acc));
#endif
}

// One block per batch element; 512 threads = one output element each.
// Per step: stream QW (512KB fp16) at 16B/lane, h_{t-1} from LDS (fp16,
// ds_read_b128 broadcast), v_dot2_f32_f16 accumulate in fp32.
__global__ __launch_bounds__(512) void rnn_fp16_k(
    const float* __restrict__ pre,     // [512][512] per batch, both biases folded
    const float4* __restrict__ QW,     // packed fp16 w_hh
    float* __restrict__ out) {         // [512][512] per batch
  const int b = blockIdx.x;
  const int o = threadIdx.x;
  __shared__ __half hsh[512];
  hsh[o] = __float2half(0.f);
  __syncthreads();
  const float* preb = pre + (size_t)b * 262144;
  float* outb = out + (size_t)b * 262144;
  const float4* qrow = QW + o;                   // + j4*512 per iter
  const float4* hs4 = (const float4*)hsh;        // 8 fp16 per entry

  for (int t = 0; t < 512; t++) {
    float a0 = preb[t * 512 + o];
    float a1 = 0.f, a2 = 0.f, a3 = 0.f;
#pragma unroll 8
    for (int j4 = 0; j4 < 64; j4++) {
      float4 q = qrow[j4 << 9];                  // 8 fp16 of W row o
      float4 hq = hs4[j4];                       // 8 fp16 of h (broadcast)
      a0 = dot2acc(q.x, hq.x, a0);
      a1 = dot2acc(q.y, hq.y, a1);
      a2 = dot2acc(q.z, hq.z, a2);
      a3 = dot2acc(q.w, hq.w, a3);
    }
    float hn = tanhf((a0 + a1) + (a2 + a3));
    __syncthreads();                             // all h reads of step t done
    hsh[o] = __float2half(hn);
    outb[t * 512 + o] = hn;
    __syncthreads();                             // h_t visible
  }
}

extern "C" void kernel_launch(void* const* d_in, const int* in_sizes, int n_in,
                              void* d_out, int out_size, void* d_ws, size_t ws_size,
                              hipStream_t stream) {
  const float* x     = (const float*)d_in[0];
  const float* fp    = (const float*)d_in[1];
  const float* fc0_w = (const float*)d_in[2];
  const float* fc0_b = (const float*)d_in[3];
  const float* fc1_w = (const float*)d_in[4];
  const float* fc1_b = (const float*)d_in[5];
  const float* fc2_w = (const float*)d_in[6];
  const float* fc2_b = (const float*)d_in[7];
  const float* fc3_w = (const float*)d_in[8];
  const float* fc3_b = (const float*)d_in[9];
  const float* w_ih0 = (const float*)d_in[10];
  const float* w_hh0 = (const float*)d_in[11];
  const float* b_ih0 = (const float*)d_in[12];
  const float* b_hh0 = (const float*)d_in[13];
  const float* w_ih1 = (const float*)d_in[14];
  const float* w_hh1 = (const float*)d_in[15];
  const float* b_ih1 = (const float*)d_in[16];
  const float* b_hh1 = (const float*)d_in[17];
  float* out = (float*)d_out;
  float* ws  = (float*)d_ws;

  float* pre = ws;                    // 16,777,216 floats
  float* t0  = pre + 16777216;        // 4,194,304
  float* t1  = t0 + 4194304;          // 4,194,304
  float* zc  = t1 + 4194304;          // 819,200
  float* f3  = zc + 819200;           // 524,288
  float4* QW0 = (float4*)(f3 + 524288);   // 32768 float4 = 131072 floats
  float4* QW1 = QW0 + 32768;              // 131072 floats
  // total ~26.77M floats = 107.1 MB

  pack_whh_fp16<<<128, 256, 0, stream>>>(w_hh0, QW0);
  pack_whh_fp16<<<128, 256, 0, stream>>>(w_hh1, QW1);

  const int CH = 4096;  // 32768 rows in 8 chunks
  for (int c = 0; c < 8; c++) {
    size_t row0 = (size_t)c * CH;
    fuzzy_kernel<<<(CH * 200 + 255) / 256, 256, 0, stream>>>(x + row0 * 50, fp, zc, CH);
    gemm_bias<<<dim3(8, 32), 256, 0, stream>>>(zc, fc0_w, fc0_b, nullptr, t0, CH, 1024, 200);
    gemm_bias<<<dim3(8, 32), 256, 0, stream>>>(t0, fc1_w, fc1_b, nullptr, t1, CH, 1024, 1024);
    gemm_bias<<<dim3(8, 32), 256, 0, stream>>>(t1, fc2_w, fc2_b, nullptr, t0, CH, 1024, 1024);
    gemm_bias<<<dim3(1, 32), 256, 0, stream>>>(t0, fc3_w, fc3_b, nullptr, f3, CH, 128, 1024);
    gemm_bias<<<dim3(4, 32), 256, 0, stream>>>(f3, w_ih0, b_ih0, b_hh0,
                                               pre + row0 * 512, CH, 512, 128);
  }

  // RNN layer 0: pre -> h0 sequence (staged in d_out)
  rnn_fp16_k<<<64, 512, 0, stream>>>(pre, QW0, out);
  // pre1 = h0 @ w_ih1^T + b_ih1 + b_hh1
  gemm_bias<<<dim3(4, 256), 256, 0, stream>>>(out, w_ih1, b_ih1, b_hh1, pre, 32768, 512, 512);
  // RNN layer 1: pre -> final output
  rnn_fp16_k<<<64, 512, 0, stream>>>(pre, QW1, out);
}

// Round 4
// 4789.779 us; speedup vs baseline: 8.6198x; 1.6720x over previous
//
#include <hip/hip_runtime.h>
#include <hip/hip_fp16.h>
#include <cstddef>

// FDRNN: fuzzy -> FC(200->1024->1024->1024->128) -> 2-layer tanh RNN (H=512)
// B=64, S=512 -> 32768 rows.
//
// R3 matched model: rnn = per-CU L2 load-port bound on the W fp16 stream
// (512KB/step -> 2.0ms/layer). R4 change: FC stack moved to fp16 MFMA
// (16x16x32, m97 structure: 128x128 tile, BK=32, global_load_lds width=16,
// 2-barrier K-loop). All FC intermediates + pre fp16; fp32 accum; biases fp32.

typedef _Float16 half8 __attribute__((ext_vector_type(8)));
typedef float f32x4 __attribute__((ext_vector_type(4)));

__device__ __forceinline__ void gld_lds16(const void* g, void* lds) {
  __builtin_amdgcn_global_load_lds(
      (const __attribute__((address_space(1))) unsigned int*)g,
      (__attribute__((address_space(3))) unsigned int*)lds, 16, 0, 0);
}

// ---------------- fuzzy (fp16 out, K padded 200->256) ----------------
__global__ void fuzzy16(const float* __restrict__ x, const float* __restrict__ fp,
                        _Float16* __restrict__ z, int nrows) {
  int idx = blockIdx.x * blockDim.x + threadIdx.x;
  if (idx >= nrows * 256) return;
  int r = idx >> 8;
  int f = idx & 255;
  float v = 0.f;
  if (f < 200) {
    int i = f % 50;
    float xv = x[r * 50 + i];
    float mu = fp[2 * f];
    float sg = fp[2 * f + 1];
    float d = xv - mu;
    v = expf(-(d * d) / sg);
  }
  z[idx] = (_Float16)v;
}

// ---------------- weight fp32 -> fp16 (with optional K zero-pad) -------------
__global__ void cvt_w16(const float* __restrict__ W, _Float16* __restrict__ O,
                        int rows, int kin, int kpad) {
  int idx = blockIdx.x * blockDim.x + threadIdx.x;
  if (idx >= rows * kpad) return;
  int r = idx / kpad;
  int k = idx - r * kpad;
  O[idx] = (k < kin) ? (_Float16)W[(size_t)r * kin + k] : (_Float16)0.f;
}

// ---------------- MFMA fp16 GEMM: C16[M][N] = A16[M][K] @ W16[N][K]^T + b ----
// 256 thr = 4 waves (2x2 of 64x64). BK=32. M%128==0, N%128==0, K%32==0.
__global__ __launch_bounds__(256) void gemm16(
    const _Float16* __restrict__ A, const _Float16* __restrict__ W,
    const float* __restrict__ b1, const float* __restrict__ b2,
    _Float16* __restrict__ C, int M, int N, int K) {
  __shared__ _Float16 As[128 * 32];
  __shared__ _Float16 Bs[128 * 32];
  const int tid = threadIdx.x;
  const int bm = blockIdx.y * 128;
  const int bn = blockIdx.x * 128;
  const int lane = tid & 63;
  const int wv = tid >> 6;
  const int wm = (wv >> 1) * 64;
  const int wn = (wv & 1) * 64;
  const int frow = lane & 15;
  const int fk = (lane >> 4) * 8;

  // staging: thread t covers row t>>2 (and +64), 16B chunk t&3
  const int srow = tid >> 2;
  const int scol = (tid & 3) * 16;  // bytes
  const char* gA = (const char*)(A + (size_t)(bm + srow) * K) + scol;
  const char* gB = (const char*)(W + (size_t)(bn + srow) * K) + scol;
  const size_t rowstep = (size_t)64 * K * 2;  // +64 rows, bytes
  char* lA = (char*)As + tid * 16;
  char* lB = (char*)Bs + tid * 16;

  f32x4 acc[4][4] = {};

  for (int k0 = 0; k0 < K; k0 += 32) {
    gld_lds16(gA, lA);
    gld_lds16(gA + rowstep, lA + 4096);
    gld_lds16(gB, lB);
    gld_lds16(gB + rowstep, lB + 4096);
    gA += 64;  // 32 halves
    gB += 64;
    __syncthreads();  // drains vmcnt -> LDS valid
    half8 af[4], bf[4];
#pragma unroll
    for (int i = 0; i < 4; i++) {
      af[i] = *(const half8*)(As + (wm + i * 16 + frow) * 32 + fk);
      bf[i] = *(const half8*)(Bs + (wn + i * 16 + frow) * 32 + fk);
    }
#pragma unroll
    for (int i = 0; i < 4; i++)
#pragma unroll
      for (int j = 0; j < 4; j++)
        acc[i][j] = __builtin_amdgcn_mfma_f32_16x16x32_f16(af[i], bf[j], acc[i][j], 0, 0, 0);
    __syncthreads();  // all reads done before next stage
  }

  float bias[4];
#pragma unroll
  for (int j = 0; j < 4; j++) {
    int col = bn + wn + j * 16 + frow;
    bias[j] = b1[col] + (b2 ? b2[col] : 0.f);
  }
  const int r0 = (lane >> 4) * 4;
#pragma unroll
  for (int i = 0; i < 4; i++) {
#pragma unroll
    for (int r = 0; r < 4; r++) {
      int row = bm + wm + i * 16 + r0 + r;
      _Float16* Cp = C + (size_t)row * N + bn + wn + frow;
#pragma unroll
      for (int j = 0; j < 4; j++)
        Cp[j * 16] = (_Float16)(acc[i][j][r] + bias[j]);
    }
  }
}

// ---------------- RNN weight pack (fp32 -> fp16, 16B groups) ----------------
// QW[j4*512 + o] = 8 fp16 = w_hh[o][8*j4 .. 8*j4+7]
__global__ void pack_whh_fp16(const float* __restrict__ W, float4* __restrict__ QW) {
  int idx = blockIdx.x * blockDim.x + threadIdx.x;
  if (idx >= 32768) return;
  int j4 = idx >> 9;
  int o = idx & 511;
  const float* src = W + (size_t)o * 512 + j4 * 8;
  __align__(16) __half2 p[4];
#pragma unroll
  for (int k = 0; k < 4; k++)
    p[k] = __halves2half2(__float2half(src[2 * k]), __float2half(src[2 * k + 1]));
  QW[idx] = *(const float4*)p;
}

typedef _Float16 v2h __attribute__((ext_vector_type(2)));

__device__ __forceinline__ float dot2acc(float wbits, float hbits, float acc) {
#if __has_builtin(__builtin_amdgcn_fdot2)
  return __builtin_amdgcn_fdot2(__builtin_bit_cast(v2h, wbits),
                                __builtin_bit_cast(v2h, hbits), acc, false);
#else
  float2 wf = __half22float2(__builtin_bit_cast(__half2, wbits));
  float2 hf = __half22float2(__builtin_bit_cast(__half2, hbits));
  return fmaf(wf.x, hf.x, fmaf(wf.y, hf.y, acc));
#endif
}

// ---------------- RNN: one block per batch, W fp16 stream ----------------
__global__ __launch_bounds__(512) void rnn_fp16_k(
    const _Float16* __restrict__ pre,  // [512][512] per batch, biases folded
    const float4* __restrict__ QW,     // packed fp16 w_hh
    float* __restrict__ out32,         // nullable: final fp32 output
    _Float16* __restrict__ out16) {    // nullable: fp16 h for next-layer GEMM
  const int b = blockIdx.x;
  const int o = threadIdx.x;
  __shared__ __half hsh[512];
  hsh[o] = __float2half(0.f);
  __syncthreads();
  const _Float16* preb = pre + (size_t)b * 262144;
  float* ob32 = out32 ? out32 + (size_t)b * 262144 : nullptr;
  _Float16* ob16 = out16 ? out16 + (size_t)b * 262144 : nullptr;
  const float4* qrow = QW + o;
  const float4* hs4 = (const float4*)hsh;

  for (int t = 0; t < 512; t++) {
    float a0 = (float)preb[t * 512 + o];
    float a1 = 0.f, a2 = 0.f, a3 = 0.f;
#pragma unroll 8
    for (int j4 = 0; j4 < 64; j4++) {
      float4 q = qrow[j4 << 9];
      float4 hq = hs4[j4];
      a0 = dot2acc(q.x, hq.x, a0);
      a1 = dot2acc(q.y, hq.y, a1);
      a2 = dot2acc(q.z, hq.z, a2);
      a3 = dot2acc(q.w, hq.w, a3);
    }
    float hn = tanhf((a0 + a1) + (a2 + a3));
    __syncthreads();
    hsh[o] = __float2half(hn);
    if (ob32) ob32[t * 512 + o] = hn;
    if (ob16) ob16[t * 512 + o] = (_Float16)hn;
    __syncthreads();
  }
}

extern "C" void kernel_launch(void* const* d_in, const int* in_sizes, int n_in,
                              void* d_out, int out_size, void* d_ws, size_t ws_size,
                              hipStream_t stream) {
  const float* x     = (const float*)d_in[0];
  const float* fp    = (const float*)d_in[1];
  const float* fc0_w = (const float*)d_in[2];
  const float* fc0_b = (const float*)d_in[3];
  const float* fc1_w = (const float*)d_in[4];
  const float* fc1_b = (const float*)d_in[5];
  const float* fc2_w = (const float*)d_in[6];
  const float* fc2_b = (const float*)d_in[7];
  const float* fc3_w = (const float*)d_in[8];
  const float* fc3_b = (const float*)d_in[9];
  const float* w_ih0 = (const float*)d_in[10];
  const float* w_hh0 = (const float*)d_in[11];
  const float* b_ih0 = (const float*)d_in[12];
  const float* b_hh0 = (const float*)d_in[13];
  const float* w_ih1 = (const float*)d_in[14];
  const float* w_hh1 = (const float*)d_in[15];
  const float* b_ih1 = (const float*)d_in[16];
  const float* b_hh1 = (const float*)d_in[17];
  float* out = (float*)d_out;
  float* ws  = (float*)d_ws;

  // ws layout (float offsets; all 16B-aligned). Total 18,448,384 fl = 73.8 MB.
  _Float16* preH = (_Float16*)ws;                    // [32768][512] fp16
  float* U = ws + 8388608;                           // 33.55MB union region
  _Float16* h16 = (_Float16*)U;                      // RNN phase: [32768][512]
  _Float16* t0  = (_Float16*)U;                      // FC phase: [8192][1024]
  float* R2 = U + 4194304;
  _Float16* t1  = (_Float16*)R2;                     // [8192][1024]
  _Float16* zc  = (_Float16*)R2;                     // [8192][256] (dead when t1 live)
  _Float16* f3  = (_Float16*)(R2 + 1048576);         // [8192][128] (t1 dead by then)
  float* wbase = ws + 16777216;
  float4*   QW0   = (float4*)wbase;                  // 131,072 fl
  float4*   QW1   = (float4*)(wbase + 131072);       // 131,072
  _Float16* fc0h  = (_Float16*)(wbase + 262144);     // 1024x256 -> 131,072 fl
  _Float16* fc1h  = (_Float16*)(wbase + 393216);     // 1024x1024 -> 524,288
  _Float16* fc2h  = (_Float16*)(wbase + 917504);     // 524,288
  _Float16* fc3h  = (_Float16*)(wbase + 1441792);    // 128x1024 -> 65,536
  _Float16* wih0h = (_Float16*)(wbase + 1507328);    // 512x128 -> 32,768
  _Float16* wih1h = (_Float16*)(wbase + 1540096);    // 512x512 -> 131,072

  pack_whh_fp16<<<128, 256, 0, stream>>>(w_hh0, QW0);
  pack_whh_fp16<<<128, 256, 0, stream>>>(w_hh1, QW1);
  cvt_w16<<<1024, 256, 0, stream>>>(fc0_w, fc0h, 1024, 200, 256);
  cvt_w16<<<4096, 256, 0, stream>>>(fc1_w, fc1h, 1024, 1024, 1024);
  cvt_w16<<<4096, 256, 0, stream>>>(fc2_w, fc2h, 1024, 1024, 1024);
  cvt_w16<<<512, 256, 0, stream>>>(fc3_w, fc3h, 128, 1024, 1024);
  cvt_w16<<<256, 256, 0, stream>>>(w_ih0, wih0h, 512, 128, 128);
  cvt_w16<<<1024, 256, 0, stream>>>(w_ih1, wih1h, 512, 512, 512);

  const int CH = 8192;  // 32768 rows in 4 chunks
  for (int c = 0; c < 4; c++) {
    size_t row0 = (size_t)c * CH;
    fuzzy16<<<CH, 256, 0, stream>>>(x + row0 * 50, fp, zc, CH);
    gemm16<<<dim3(8, 64), 256, 0, stream>>>(zc, fc0h, fc0_b, nullptr, t0, CH, 1024, 256);
    gemm16<<<dim3(8, 64), 256, 0, stream>>>(t0, fc1h, fc1_b, nullptr, t1, CH, 1024, 1024);
    gemm16<<<dim3(8, 64), 256, 0, stream>>>(t1, fc2h, fc2_b, nullptr, t0, CH, 1024, 1024);
    gemm16<<<dim3(1, 64), 256, 0, stream>>>(t0, fc3h, fc3_b, nullptr, f3, CH, 128, 1024);
    gemm16<<<dim3(4, 64), 256, 0, stream>>>(f3, wih0h, b_ih0, b_hh0,
                                            preH + row0 * 512, CH, 512, 128);
  }

  // RNN layer 0: preH -> h16 (fp16, feeds layer-1 input projection)
  rnn_fp16_k<<<64, 512, 0, stream>>>(preH, QW0, nullptr, h16);
  // pre1 = h0 @ w_ih1^T + b_ih1 + b_hh1 (fp16 out into preH)
  gemm16<<<dim3(4, 256), 256, 0, stream>>>(h16, wih1h, b_ih1, b_hh1, preH, 32768, 512, 512);
  // RNN layer 1: preH -> final fp32 output
  rnn_fp16_k<<<64, 512, 0, stream>>>(preH, QW1, out, nullptr);
}

// Round 5
// 3274.722 us; speedup vs baseline: 12.6078x; 1.4627x over previous
//
#include <hip/hip_runtime.h>
#include <hip/hip_fp16.h>
#include <cstddef>

// FDRNN: fuzzy -> FC(200->1024->1024->1024->128) -> 2-layer tanh RNN (H=512)
// B=64, S=512 -> 32768 rows.
//
// R4: FC stack on fp16 MFMA (validated, ~0.55ms). RNN = 2x2.11ms, per-CU L2
// load-port bound re-reading 512KB W/step.
// R5 change: W_hh made CU-resident: 288 j in VGPRs (144/thread, unrolled
// component access only -- R2's spill came from an address-taken cast),
// 48 j in LDS (48KB), 176 j streamed. Model: 3380 cyc/step -> ~0.72ms/layer.

typedef _Float16 half8 __attribute__((ext_vector_type(8)));
typedef float f32x4 __attribute__((ext_vector_type(4)));

__device__ __forceinline__ void gld_lds16(const void* g, void* lds) {
  __builtin_amdgcn_global_load_lds(
      (const __attribute__((address_space(1))) unsigned int*)g,
      (__attribute__((address_space(3))) unsigned int*)lds, 16, 0, 0);
}

// ---------------- fuzzy (fp16 out, K padded 200->256) ----------------
__global__ void fuzzy16(const float* __restrict__ x, const float* __restrict__ fp,
                        _Float16* __restrict__ z, int nrows) {
  int idx = blockIdx.x * blockDim.x + threadIdx.x;
  if (idx >= nrows * 256) return;
  int r = idx >> 8;
  int f = idx & 255;
  float v = 0.f;
  if (f < 200) {
    int i = f % 50;
    float xv = x[r * 50 + i];
    float mu = fp[2 * f];
    float sg = fp[2 * f + 1];
    float d = xv - mu;
    v = expf(-(d * d) / sg);
  }
  z[idx] = (_Float16)v;
}

// ---------------- weight fp32 -> fp16 (with optional K zero-pad) -------------
__global__ void cvt_w16(const float* __restrict__ W, _Float16* __restrict__ O,
                        int rows, int kin, int kpad) {
  int idx = blockIdx.x * blockDim.x + threadIdx.x;
  if (idx >= rows * kpad) return;
  int r = idx / kpad;
  int k = idx - r * kpad;
  O[idx] = (k < kin) ? (_Float16)W[(size_t)r * kin + k] : (_Float16)0.f;
}

// ---------------- MFMA fp16 GEMM: C16[M][N] = A16[M][K] @ W16[N][K]^T + b ----
__global__ __launch_bounds__(256) void gemm16(
    const _Float16* __restrict__ A, const _Float16* __restrict__ W,
    const float* __restrict__ b1, const float* __restrict__ b2,
    _Float16* __restrict__ C, int M, int N, int K) {
  __shared__ _Float16 As[128 * 32];
  __shared__ _Float16 Bs[128 * 32];
  const int tid = threadIdx.x;
  const int bm = blockIdx.y * 128;
  const int bn = blockIdx.x * 128;
  const int lane = tid & 63;
  const int wv = tid >> 6;
  const int wm = (wv >> 1) * 64;
  const int wn = (wv & 1) * 64;
  const int frow = lane & 15;
  const int fk = (lane >> 4) * 8;

  const int srow = tid >> 2;
  const int scol = (tid & 3) * 16;  // bytes
  const char* gA = (const char*)(A + (size_t)(bm + srow) * K) + scol;
  const char* gB = (const char*)(W + (size_t)(bn + srow) * K) + scol;
  const size_t rowstep = (size_t)64 * K * 2;
  char* lA = (char*)As + tid * 16;
  char* lB = (char*)Bs + tid * 16;

  f32x4 acc[4][4] = {};

  for (int k0 = 0; k0 < K; k0 += 32) {
    gld_lds16(gA, lA);
    gld_lds16(gA + rowstep, lA + 4096);
    gld_lds16(gB, lB);
    gld_lds16(gB + rowstep, lB + 4096);
    gA += 64;
    gB += 64;
    __syncthreads();
    half8 af[4], bf[4];
#pragma unroll
    for (int i = 0; i < 4; i++) {
      af[i] = *(const half8*)(As + (wm + i * 16 + frow) * 32 + fk);
      bf[i] = *(const half8*)(Bs + (wn + i * 16 + frow) * 32 + fk);
    }
#pragma unroll
    for (int i = 0; i < 4; i++)
#pragma unroll
      for (int j = 0; j < 4; j++)
        acc[i][j] = __builtin_amdgcn_mfma_f32_16x16x32_f16(af[i], bf[j], acc[i][j], 0, 0, 0);
    __syncthreads();
  }

  float bias[4];
#pragma unroll
  for (int j = 0; j < 4; j++) {
    int col = bn + wn + j * 16 + frow;
    bias[j] = b1[col] + (b2 ? b2[col] : 0.f);
  }
  const int r0 = (lane >> 4) * 4;
#pragma unroll
  for (int i = 0; i < 4; i++) {
#pragma unroll
    for (int r = 0; r < 4; r++) {
      int row = bm + wm + i * 16 + r0 + r;
      _Float16* Cp = C + (size_t)row * N + bn + wn + frow;
#pragma unroll
      for (int j = 0; j < 4; j++)
        Cp[j * 16] = (_Float16)(acc[i][j][r] + bias[j]);
    }
  }
}

// ---------------- RNN weight pack (fp32 -> fp16, 16B groups) ----------------
// QW[j4*512 + o] = 8 fp16 = w_hh[o][8*j4 .. 8*j4+7]
__global__ void pack_whh_fp16(const float* __restrict__ W, float4* __restrict__ QW) {
  int idx = blockIdx.x * blockDim.x + threadIdx.x;
  if (idx >= 32768) return;
  int j4 = idx >> 9;
  int o = idx & 511;
  const float* src = W + (size_t)o * 512 + j4 * 8;
  __align__(16) __half2 p[4];
#pragma unroll
  for (int k = 0; k < 4; k++)
    p[k] = __halves2half2(__float2half(src[2 * k]), __float2half(src[2 * k + 1]));
  QW[idx] = *(const float4*)p;
}

typedef _Float16 v2h __attribute__((ext_vector_type(2)));

__device__ __forceinline__ float dot2acc(float wbits, float hbits, float acc) {
#if __has_builtin(__builtin_amdgcn_fdot2)
  return __builtin_amdgcn_fdot2(__builtin_bit_cast(v2h, wbits),
                                __builtin_bit_cast(v2h, hbits), acc, false);
#else
  float2 wf = __half22float2(__builtin_bit_cast(__half2, wbits));
  float2 hf = __half22float2(__builtin_bit_cast(__half2, hbits));
  return fmaf(wf.x, hf.x, fmaf(wf.y, hf.y, acc));
#endif
}

// ---------------- RNN: one block per batch, W CU-resident ----------------
// j4 groups (8 fp16 each, 64 total): [0,36) regs, [36,42) LDS, [42,64) stream.
#define JR4 36
#define JL4 6
#define JS4 22

__global__ __launch_bounds__(512, 2) void rnn_resident_k(
    const _Float16* __restrict__ pre,  // [512][512] per batch, biases folded
    const float4* __restrict__ QW,     // packed fp16 w_hh
    float* __restrict__ out32,         // nullable: final fp32 output
    _Float16* __restrict__ out16) {    // nullable: fp16 h for next-layer GEMM
  const int b = blockIdx.x;
  const int o = threadIdx.x;
  __shared__ __half hsh[512];
  __shared__ float4 wlds[JL4][512];    // 48 KB

  const float4* qrow = QW + o;
  // Register-resident W: 36 float4 = 144 VGPR. Component access only.
  float4 w[JR4];
#pragma unroll
  for (int k = 0; k < JR4; k++) w[k] = qrow[k << 9];
  // LDS-resident W
#pragma unroll
  for (int k = 0; k < JL4; k++) wlds[k][o] = qrow[(JR4 + k) << 9];
  hsh[o] = __float2half(0.f);
  __syncthreads();

  const _Float16* preb = pre + (size_t)b * 262144;
  float* ob32 = out32 ? out32 + (size_t)b * 262144 : nullptr;
  _Float16* ob16 = out16 ? out16 + (size_t)b * 262144 : nullptr;
  const float4* hs4 = (const float4*)hsh;

  for (int t = 0; t < 512; t++) {
    float a0 = (float)preb[t * 512 + o];
    float a1 = 0.f, a2 = 0.f, a3 = 0.f;
    // register section: j 0..287
#pragma unroll
    for (int k = 0; k < JR4; k++) {
      float4 hq = hs4[k];
      a0 = dot2acc(w[k].x, hq.x, a0);
      a1 = dot2acc(w[k].y, hq.y, a1);
      a2 = dot2acc(w[k].z, hq.z, a2);
      a3 = dot2acc(w[k].w, hq.w, a3);
    }
    // LDS section: j 288..335
#pragma unroll
    for (int k = 0; k < JL4; k++) {
      float4 q = wlds[k][o];
      float4 hq = hs4[JR4 + k];
      a0 = dot2acc(q.x, hq.x, a0);
      a1 = dot2acc(q.y, hq.y, a1);
      a2 = dot2acc(q.z, hq.z, a2);
      a3 = dot2acc(q.w, hq.w, a3);
    }
    // streamed section: j 336..511, two chunks to bound load live-ranges
#pragma unroll
    for (int c = 0; c < 2; c++) {
      float4 qs[11];
#pragma unroll
      for (int k = 0; k < 11; k++)
        qs[k] = qrow[(JR4 + JL4 + c * 11 + k) << 9];
#pragma unroll
      for (int k = 0; k < 11; k++) {
        float4 hq = hs4[JR4 + JL4 + c * 11 + k];
        a0 = dot2acc(qs[k].x, hq.x, a0);
        a1 = dot2acc(qs[k].y, hq.y, a1);
        a2 = dot2acc(qs[k].z, hq.z, a2);
        a3 = dot2acc(qs[k].w, hq.w, a3);
      }
    }
    float hn = tanhf((a0 + a1) + (a2 + a3));
    __syncthreads();
    hsh[o] = __float2half(hn);
    if (ob32) ob32[t * 512 + o] = hn;
    if (ob16) ob16[t * 512 + o] = (_Float16)hn;
    __syncthreads();
  }
}

extern "C" void kernel_launch(void* const* d_in, const int* in_sizes, int n_in,
                              void* d_out, int out_size, void* d_ws, size_t ws_size,
                              hipStream_t stream) {
  const float* x     = (const float*)d_in[0];
  const float* fp    = (const float*)d_in[1];
  const float* fc0_w = (const float*)d_in[2];
  const float* fc0_b = (const float*)d_in[3];
  const float* fc1_w = (const float*)d_in[4];
  const float* fc1_b = (const float*)d_in[5];
  const float* fc2_w = (const float*)d_in[6];
  const float* fc2_b = (const float*)d_in[7];
  const float* fc3_w = (const float*)d_in[8];
  const float* fc3_b = (const float*)d_in[9];
  const float* w_ih0 = (const float*)d_in[10];
  const float* w_hh0 = (const float*)d_in[11];
  const float* b_ih0 = (const float*)d_in[12];
  const float* b_hh0 = (const float*)d_in[13];
  const float* w_ih1 = (const float*)d_in[14];
  const float* w_hh1 = (const float*)d_in[15];
  const float* b_ih1 = (const float*)d_in[16];
  const float* b_hh1 = (const float*)d_in[17];
  float* out = (float*)d_out;
  float* ws  = (float*)d_ws;

  // ws layout (float offsets). Total ~73.8 MB.
  _Float16* preH = (_Float16*)ws;                    // [32768][512] fp16
  float* U = ws + 8388608;
  _Float16* h16 = (_Float16*)U;                      // RNN phase: [32768][512]
  _Float16* t0  = (_Float16*)U;                      // FC phase: [8192][1024]
  float* R2 = U + 4194304;
  _Float16* t1  = (_Float16*)R2;                     // [8192][1024]
  _Float16* zc  = (_Float16*)R2;                     // [8192][256]
  _Float16* f3  = (_Float16*)(R2 + 1048576);         // [8192][128]
  float* wbase = ws + 16777216;
  float4*   QW0   = (float4*)wbase;
  float4*   QW1   = (float4*)(wbase + 131072);
  _Float16* fc0h  = (_Float16*)(wbase + 262144);
  _Float16* fc1h  = (_Float16*)(wbase + 393216);
  _Float16* fc2h  = (_Float16*)(wbase + 917504);
  _Float16* fc3h  = (_Float16*)(wbase + 1441792);
  _Float16* wih0h = (_Float16*)(wbase + 1507328);
  _Float16* wih1h = (_Float16*)(wbase + 1540096);

  pack_whh_fp16<<<128, 256, 0, stream>>>(w_hh0, QW0);
  pack_whh_fp16<<<128, 256, 0, stream>>>(w_hh1, QW1);
  cvt_w16<<<1024, 256, 0, stream>>>(fc0_w, fc0h, 1024, 200, 256);
  cvt_w16<<<4096, 256, 0, stream>>>(fc1_w, fc1h, 1024, 1024, 1024);
  cvt_w16<<<4096, 256, 0, stream>>>(fc2_w, fc2h, 1024, 1024, 1024);
  cvt_w16<<<512, 256, 0, stream>>>(fc3_w, fc3h, 128, 1024, 1024);
  cvt_w16<<<256, 256, 0, stream>>>(w_ih0, wih0h, 512, 128, 128);
  cvt_w16<<<1024, 256, 0, stream>>>(w_ih1, wih1h, 512, 512, 512);

  const int CH = 8192;  // 32768 rows in 4 chunks
  for (int c = 0; c < 4; c++) {
    size_t row0 = (size_t)c * CH;
    fuzzy16<<<CH, 256, 0, stream>>>(x + row0 * 50, fp, zc, CH);
    gemm16<<<dim3(8, 64), 256, 0, stream>>>(zc, fc0h, fc0_b, nullptr, t0, CH, 1024, 256);
    gemm16<<<dim3(8, 64), 256, 0, stream>>>(t0, fc1h, fc1_b, nullptr, t1, CH, 1024, 1024);
    gemm16<<<dim3(8, 64), 256, 0, stream>>>(t1, fc2h, fc2_b, nullptr, t0, CH, 1024, 1024);
    gemm16<<<dim3(1, 64), 256, 0, stream>>>(t0, fc3h, fc3_b, nullptr, f3, CH, 128, 1024);
    gemm16<<<dim3(4, 64), 256, 0, stream>>>(f3, wih0h, b_ih0, b_hh0,
                                            preH + row0 * 512, CH, 512, 128);
  }

  // RNN layer 0: preH -> h16 (fp16, feeds layer-1 input projection)
  rnn_resident_k<<<64, 512, 0, stream>>>(preH, QW0, nullptr, h16);
  // pre1 = h0 @ w_ih1^T + b_ih1 + b_hh1 (fp16 out into preH)
  gemm16<<<dim3(4, 256), 256, 0, stream>>>(h16, wih1h, b_ih1, b_hh1, preH, 32768, 512, 512);
  // RNN layer 1: preH -> final fp32 output
  rnn_resident_k<<<64, 512, 0, stream>>>(preH, QW1, out, nullptr);
}